// Round 13
// baseline (828.417 us; speedup 1.0000x reference)
//
#include <hip/hip_runtime.h>
#include <hip/hip_bf16.h>
#include <math.h>

#define N_NODES 50000
#define N_EDGES 600000
#define DIM 128
#define N_REL 8
#define N_GRAPHS 256
#define NBN 64                // nodes per block (grid 782, single scheduling wave)
#define NBLK ((N_NODES + NBN - 1) / NBN)  // 782
#define KDIM (N_REL * DIM)    // relation-stacked K = 1024
#define NKEY (N_NODES * N_REL)  // 400000 (node,rel) keys
#define SEG 1024
#define NSEG2 391             // ceil(400000/1024); NSEG2*SEG = 400384

typedef __attribute__((ext_vector_type(8))) short short8;
typedef __attribute__((ext_vector_type(4))) float floatx4;
typedef __attribute__((ext_vector_type(4))) float f32x4;
typedef unsigned int uint;
typedef unsigned short ushort;

static __device__ __forceinline__ int lower_bound_i(const int* a, int n, int v) {
    int lo = 0, hi = n;
    while (lo < hi) { int mid = (lo + hi) >> 1; if (a[mid] < v) lo = mid + 1; else hi = mid; }
    return lo;
}

// RNE float->bf16 split: .x = bf16(x)|bf16(y)<<16 (hi), .y = same for residuals (lo)
static __device__ __forceinline__ uint2 split2(float x, float y) {
    uint ux = __float_as_uint(x);
    uint hx = (ux + 0x7FFFu + ((ux >> 16) & 1u)) & 0xFFFF0000u;
    float rx = x - __uint_as_float(hx);
    uint urx = __float_as_uint(rx);
    uint lx = (urx + 0x7FFFu + ((urx >> 16) & 1u)) >> 16;
    uint uy = __float_as_uint(y);
    uint hy = (uy + 0x7FFFu + ((uy >> 16) & 1u)) & 0xFFFF0000u;
    float ry = y - __uint_as_float(hy);
    uint ury = __float_as_uint(ry);
    uint ly = (ury + 0x7FFFu + ((ury >> 16) & 1u)) >> 16;
    return make_uint2((hx >> 16) | (hy & 0xFFFF0000u), lx | (ly << 16));
}

__global__ void k_count(const int* __restrict__ dst, const int* __restrict__ etype,
                        int* __restrict__ counts, int e) {
    int i = blockIdx.x * blockDim.x + threadIdx.x;
    if (i < e) atomicAdd(&counts[dst[i] * 8 + etype[i]], 1);
}

// --- coalesced 3-kernel exclusive scan over counts[NSEG2*SEG] (padding zeroed) ---
__global__ __launch_bounds__(256) void k_scan_seg(const int* __restrict__ counts,
                                                  int* __restrict__ segscan,
                                                  int* __restrict__ segtot) {
    const int b = blockIdx.x, t = threadIdx.x;
    const int base = b * SEG + t * 4;
    const int4 v = *(const int4*)(counts + base);
    const int s0 = v.x, s1 = s0 + v.y, s2 = s1 + v.z, s3 = s2 + v.w;
    __shared__ int sl[256];
    sl[t] = s3;
    __syncthreads();
    for (int off = 1; off < 256; off <<= 1) {
        int add = (t >= off) ? sl[t - off] : 0;
        __syncthreads();
        sl[t] += add;
        __syncthreads();
    }
    const int tp = sl[t] - s3;
    int4 o;
    o.x = tp; o.y = tp + s0; o.z = tp + s1; o.w = tp + s2;
    *(int4*)(segscan + base) = o;
    if (t == 255) segtot[b] = sl[255];
}

__global__ __launch_bounds__(512) void k_scan_tot(const int* __restrict__ segtot,
                                                  int* __restrict__ segbase) {
    const int t = threadIdx.x;  // 512 threads, 1 block
    const int v = (t < NSEG2) ? segtot[t] : 0;
    __shared__ int sl[512];
    sl[t] = v;
    __syncthreads();
    for (int off = 1; off < 512; off <<= 1) {
        int u = (t >= off) ? sl[t - off] : 0;
        __syncthreads();
        sl[t] += u;
        __syncthreads();
    }
    if (t < NSEG2) segbase[t] = sl[t] - v;
    if (t == NSEG2) segbase[NSEG2] = sl[NSEG2 - 1];
}

__global__ void k_scan_fin(const int* __restrict__ segscan, const int* __restrict__ segbase,
                           int* __restrict__ offsets, int* __restrict__ cursor) {
    const int i = blockIdx.x * blockDim.x + threadIdx.x;
    if (i < NKEY) {
        const int val = segbase[i >> 10] + segscan[i];
        offsets[i] = val;
        cursor[i] = val;
    } else if (i == NKEY) {
        offsets[NKEY] = segbase[NSEG2];
    }
}

// scatter edges grouped by (dst, etype); word = src(16b) | etype(3b @16)
__global__ void k_fill(const int* __restrict__ src, const int* __restrict__ dst,
                       const int* __restrict__ etype, int* cursor,
                       int* __restrict__ edges, int e) {
    int i = blockIdx.x * blockDim.x + threadIdx.x;
    if (i < e) {
        const int et = etype[i];
        int pos = atomicAdd(&cursor[dst[i] * 8 + et], 1);
        edges[pos] = src[i] | (et << 16);
    }
}

// Fused prep: blocks 0..1535 pack W (bf16 hi/lo, MFMA fragment order, 3 layers);
// blocks 1536..1926 zero the (node,rel) counters (saves a memset launch).
__global__ void k_prep(const float* __restrict__ b1, const float* __restrict__ c1,
                       ushort* __restrict__ Whi1, ushort* __restrict__ Wlo1,
                       const float* __restrict__ b2, const float* __restrict__ c2,
                       ushort* __restrict__ Whi2, ushort* __restrict__ Wlo2,
                       const float* __restrict__ b3, const float* __restrict__ c3,
                       ushort* __restrict__ Whi3, ushort* __restrict__ Wlo3,
                       int* __restrict__ counts) {
    if (blockIdx.x >= 1536) {
        const int i = (blockIdx.x - 1536) * 1024 + threadIdx.x * 4;
        *(int4*)(counts + i) = make_int4(0, 0, 0, 0);
        return;
    }
    const int lay = blockIdx.x >> 9;  // 512 blocks per layer
    const int id = (blockIdx.x & 511) * blockDim.x + threadIdx.x;  // 0..131071
    const float* bases = (lay == 0) ? b1 : (lay == 1) ? b2 : b3;
    const float* comp  = (lay == 0) ? c1 : (lay == 1) ? c2 : c3;
    ushort* Whi = (lay == 0) ? Whi1 : (lay == 1) ? Whi2 : Whi3;
    ushort* Wlo = (lay == 0) ? Wlo1 : (lay == 1) ? Wlo2 : Wlo3;
    int nn = id & 127, k = id >> 7;
    int r = k >> 7, dk = k & 127;
    const float* cp = comp + r * 8;
    float v = 0.f;
#pragma unroll
    for (int b = 0; b < 8; b++) v = fmaf(cp[b], bases[((size_t)b * 128 + dk) * 128 + nn], v);
    uint u = __float_as_uint(v);
    uint hu = (u + 0x7FFFu + ((u >> 16) & 1u)) & 0xFFFF0000u;
    float rf = v - __uint_as_float(hu);
    uint ur = __float_as_uint(rf);
    uint lu = (ur + 0x7FFFu + ((ur >> 16) & 1u)) >> 16;
    int kt = k >> 5, kk = k & 31;
    int off = kt * 4096 + nn * 32 + kk;
    Whi[off] = (ushort)(hu >> 16);
    Wlo[off] = (ushort)lu;
}

// One RGCN layer, fused, 512 threads (8 waves), 64 nodes/block, EIGHT K-rounds
// (one relation per round, K=128 each). A stored bf16 hi+lo (3-term split =
// fp32-class accuracy — R12's 2-term failed at 7.9e-2): per-round A-LDS is
// 64 nodes x 128 k x hi/lo = 32 KB -> ~34 KB total, 4 blocks/CU.
//   round ro: aggregate relation ro per node (4 visits per half-wave, 4 dims/
//   lane, next-visit descriptor prefetch; consume = a += v, no branching),
//   unconditional flush (full slot coverage -> no zero phase); then MFMA
//   kt ro*4..+3 into persistent VGPRs (4 row-tiles/wave, 3 terms).
//   B (relation-stacked W, comp folded by k_prep) read once per 64 nodes;
//   782 blocks = single scheduling wave. CSR offsets roll across rounds
//   (eE[ro] == eS[ro+1]; one new offset load per round, prefetched during MFMA).
//  GATE (layer 3): epilogue via 16-lane shuffle reduce + LDS partials (NO
//  ATOMICS — R7 pitfall).
//
// PITFALL (R3): do NOT scalarize loads of per-call-rebuilt arrays
// (edges/offsets) — compiler s_load via scalar cache serves STALE data on
// graph replay. Keep lane-derived (vector) addressing.
// PITFALL (R7): NO per-lane float atomicAdd on LDS — compiles to CAS loop.
// PITFALL (R12): A must keep the lo term (3-term split); bf16-only A gives
// absmax ~8e-2 > 2e-2 threshold.
template <bool RELU, bool GATE>
__global__ __launch_bounds__(512, 8) void k_layer(
    const float* __restrict__ xin, float* __restrict__ hout,
    const int* __restrict__ edges, const int* __restrict__ offsets,
    const ushort* __restrict__ Whi, const ushort* __restrict__ Wlo,
    const float* __restrict__ bias,
    const float* __restrict__ gw, const float* __restrict__ gb,
    float* __restrict__ gate) {
    __shared__ ushort sHi[4 * 2048];  // 16 KiB: [ktp:4][q:4][chunk:64][8]
    __shared__ ushort sLo[4 * 2048];  // 16 KiB
    __shared__ float sgatep[NBN][8];
    const int tid = threadIdx.x;
    const int lane = tid & 63;
    const int w = tid >> 6;
    const int q2 = lane >> 4, mm = lane & 15;
    const int xev = (mm ^ q2) * 8;        // A chunk sub-offset, kt even
    const int xod = ((mm ^ q2) ^ 4) * 8;  // kt odd (parity swizzle)
    const int aq = q2 * 512;              // q-group base (ushort) within ktp
    const int n0 = w * 16 + mm;
    const ushort* bph = Whi + n0 * 32 + q2 * 8;
    const ushort* bpl = Wlo + n0 * 32 + q2 * 8;
    floatx4 acc0 = {0.f, 0.f, 0.f, 0.f};  // rows  0..15
    floatx4 acc1 = {0.f, 0.f, 0.f, 0.f};  // rows 16..31
    floatx4 acc2 = {0.f, 0.f, 0.f, 0.f};  // rows 32..47
    floatx4 acc3 = {0.f, 0.f, 0.f, 0.f};  // rows 48..63

    const int hw = tid >> 5, l5 = tid & 31;
    const int d0 = l5 * 4;
    const int kt_off = l5 >> 3;      // 0..3
    const int q = (l5 >> 1) & 3;
    const int jb = (l5 & 1) * 4;
    const int nbase = blockIdx.x * NBN + hw * 4;

    // preload round-0 CSR offset pair (lane-addressed; R3 pitfall)
    int eS[4], eE[4];
#pragma unroll
    for (int v = 0; v < 4; ++v) {
        const int n = nbase + v;
        if (n < N_NODES) { eS[v] = offsets[n * 8]; eE[v] = offsets[n * 8 + 1]; }
        else { eS[v] = 0; eE[v] = 0; }
    }

    for (int ro = 0; ro < 8; ++ro) {
        // ---- phase 1: aggregate relation ro; 4 visits per half-wave ----
        // edges[] is padded +16 so unguarded descriptor chunk reads are safe.
        int c0 = edges[eS[0]], c1 = edges[eS[0] + 1], c2 = edges[eS[0] + 2], c3 = edges[eS[0] + 3];
#pragma unroll
        for (int v = 0; v < 4; ++v) {
            // prefetch next visit's first descriptor chunk (overlaps this visit)
            int f0 = 0, f1 = 0, f2 = 0, f3 = 0;
            if (v < 3) {
                const int es = eS[v + 1];
                f0 = edges[es]; f1 = edges[es + 1]; f2 = edges[es + 2]; f3 = edges[es + 3];
            }
            f32x4 a0 = (f32x4)0.f;
            int e = eS[v]; const int e1 = eE[v];
            int p0 = c0, p1 = c1, p2 = c2, p3 = c3;
            while (e < e1) {
                const int c = e1 - e;
                f32x4 v0, v1, v2, v3;
                v0 = *(const f32x4*)(xin + (size_t)(p0 & 0xFFFF) * DIM + d0);
                if (c > 1) v1 = *(const f32x4*)(xin + (size_t)(p1 & 0xFFFF) * DIM + d0);
                if (c > 2) v2 = *(const f32x4*)(xin + (size_t)(p2 & 0xFFFF) * DIM + d0);
                if (c > 3) v3 = *(const f32x4*)(xin + (size_t)(p3 & 0xFFFF) * DIM + d0);
                a0 += v0;
                if (c > 1) a0 += v1;
                if (c > 2) a0 += v2;
                if (c > 3) a0 += v3;
                e += 4;
                if (e < e1) { p0 = edges[e]; p1 = edges[e + 1]; p2 = edges[e + 2]; p3 = edges[e + 3]; }
            }
            // unconditional flush for node m (covers every slot -> no zeroing)
            {
                const int m = hw * 4 + v;
                const int ktp = kt_off;
                const int ch = (m ^ q) ^ ((ktp & 1) << 2);
                const int u0 = ktp * 2048 + q * 512 + ch * 8 + jb;
                const uint2 p01 = split2(a0.x, a0.y);
                const uint2 p23 = split2(a0.z, a0.w);
                *(uint2*)(sHi + u0) = make_uint2(p01.x, p23.x);
                *(uint2*)(sLo + u0) = make_uint2(p01.y, p23.y);
            }
            c0 = f0; c1 = f1; c2 = f2; c3 = f3;
        }
        __syncthreads();

        // prefetch next round's end offsets (lands during MFMA below);
        // start offsets roll: eS[next] = eE[this].
        int nE[4];
        if (ro < 7) {
#pragma unroll
            for (int v = 0; v < 4; ++v) {
                const int n = nbase + v;
                nE[v] = (n < N_NODES) ? offsets[n * 8 + ro + 2] : 0;
            }
        }

        // ---- phase 2 (this K-eighth): MFMA, wave owns 16-col strip, 4 row-tiles ----
        for (int kt = 0; kt < 4; kt += 2) {
            {
                const int ktg = ro * 4 + kt;
                const ushort* ap = sHi + kt * 2048 + aq;
                const ushort* alp = sLo + kt * 2048 + aq;
                const short8 ah0 = *(const short8*)(ap + xev);
                const short8 ah1 = *(const short8*)(ap + 128 + xev);
                const short8 ah2 = *(const short8*)(ap + 256 + xev);
                const short8 ah3 = *(const short8*)(ap + 384 + xev);
                const short8 al0 = *(const short8*)(alp + xev);
                const short8 al1 = *(const short8*)(alp + 128 + xev);
                const short8 al2 = *(const short8*)(alp + 256 + xev);
                const short8 al3 = *(const short8*)(alp + 384 + xev);
                const short8 bh = *(const short8*)(bph + ktg * 4096);
                const short8 bl = *(const short8*)(bpl + ktg * 4096);
                acc0 = __builtin_amdgcn_mfma_f32_16x16x32_bf16(ah0, bh, acc0, 0, 0, 0);
                acc1 = __builtin_amdgcn_mfma_f32_16x16x32_bf16(ah1, bh, acc1, 0, 0, 0);
                acc2 = __builtin_amdgcn_mfma_f32_16x16x32_bf16(ah2, bh, acc2, 0, 0, 0);
                acc3 = __builtin_amdgcn_mfma_f32_16x16x32_bf16(ah3, bh, acc3, 0, 0, 0);
                acc0 = __builtin_amdgcn_mfma_f32_16x16x32_bf16(ah0, bl, acc0, 0, 0, 0);
                acc1 = __builtin_amdgcn_mfma_f32_16x16x32_bf16(ah1, bl, acc1, 0, 0, 0);
                acc2 = __builtin_amdgcn_mfma_f32_16x16x32_bf16(ah2, bl, acc2, 0, 0, 0);
                acc3 = __builtin_amdgcn_mfma_f32_16x16x32_bf16(ah3, bl, acc3, 0, 0, 0);
                acc0 = __builtin_amdgcn_mfma_f32_16x16x32_bf16(al0, bh, acc0, 0, 0, 0);
                acc1 = __builtin_amdgcn_mfma_f32_16x16x32_bf16(al1, bh, acc1, 0, 0, 0);
                acc2 = __builtin_amdgcn_mfma_f32_16x16x32_bf16(al2, bh, acc2, 0, 0, 0);
                acc3 = __builtin_amdgcn_mfma_f32_16x16x32_bf16(al3, bh, acc3, 0, 0, 0);
            }
            {
                const int kto = kt + 1;
                const int ktg = ro * 4 + kto;
                const ushort* ap = sHi + kto * 2048 + aq;
                const ushort* alp = sLo + kto * 2048 + aq;
                const short8 ah0 = *(const short8*)(ap + xod);
                const short8 ah1 = *(const short8*)(ap + 128 + xod);
                const short8 ah2 = *(const short8*)(ap + 256 + xod);
                const short8 ah3 = *(const short8*)(ap + 384 + xod);
                const short8 al0 = *(const short8*)(alp + xod);
                const short8 al1 = *(const short8*)(alp + 128 + xod);
                const short8 al2 = *(const short8*)(alp + 256 + xod);
                const short8 al3 = *(const short8*)(alp + 384 + xod);
                const short8 bh = *(const short8*)(bph + ktg * 4096);
                const short8 bl = *(const short8*)(bpl + ktg * 4096);
                acc0 = __builtin_amdgcn_mfma_f32_16x16x32_bf16(ah0, bh, acc0, 0, 0, 0);
                acc1 = __builtin_amdgcn_mfma_f32_16x16x32_bf16(ah1, bh, acc1, 0, 0, 0);
                acc2 = __builtin_amdgcn_mfma_f32_16x16x32_bf16(ah2, bh, acc2, 0, 0, 0);
                acc3 = __builtin_amdgcn_mfma_f32_16x16x32_bf16(ah3, bh, acc3, 0, 0, 0);
                acc0 = __builtin_amdgcn_mfma_f32_16x16x32_bf16(ah0, bl, acc0, 0, 0, 0);
                acc1 = __builtin_amdgcn_mfma_f32_16x16x32_bf16(ah1, bl, acc1, 0, 0, 0);
                acc2 = __builtin_amdgcn_mfma_f32_16x16x32_bf16(ah2, bl, acc2, 0, 0, 0);
                acc3 = __builtin_amdgcn_mfma_f32_16x16x32_bf16(ah3, bl, acc3, 0, 0, 0);
                acc0 = __builtin_amdgcn_mfma_f32_16x16x32_bf16(al0, bh, acc0, 0, 0, 0);
                acc1 = __builtin_amdgcn_mfma_f32_16x16x32_bf16(al1, bh, acc1, 0, 0, 0);
                acc2 = __builtin_amdgcn_mfma_f32_16x16x32_bf16(al2, bh, acc2, 0, 0, 0);
                acc3 = __builtin_amdgcn_mfma_f32_16x16x32_bf16(al3, bh, acc3, 0, 0, 0);
            }
        }
        if (ro < 7) {
#pragma unroll
            for (int v = 0; v < 4; ++v) { eS[v] = eE[v]; eE[v] = nE[v]; }
            __syncthreads();  // phase-2 reads done before next round's flush
        }
    }

    // ---- epilogue: bias/relu, store, optional fused gate ----
    const float b0 = bias[n0];
    const float gwn = GATE ? gw[n0] : 0.f;
    float gp0[4], gp1[4], gp2[4], gp3[4];
#pragma unroll
    for (int r = 0; r < 4; r++) {
        const int row = q2 * 4 + r;             // C/D: row=(lane>>4)*4+reg, col=lane&15
        const int nA = blockIdx.x * NBN + row;
        const int nB = nA + 16, nC = nA + 32, nD = nA + 48;
        float v0 = acc0[r] + b0, v1 = acc1[r] + b0, v2 = acc2[r] + b0, v3 = acc3[r] + b0;
        if (RELU) { v0 = fmaxf(v0, 0.f); v1 = fmaxf(v1, 0.f); v2 = fmaxf(v2, 0.f); v3 = fmaxf(v3, 0.f); }
        if (nA < N_NODES) hout[(size_t)nA * DIM + n0] = v0;
        if (nB < N_NODES) hout[(size_t)nB * DIM + n0] = v1;
        if (nC < N_NODES) hout[(size_t)nC * DIM + n0] = v2;
        if (nD < N_NODES) hout[(size_t)nD * DIM + n0] = v3;
        if (GATE) { gp0[r] = v0 * gwn; gp1[r] = v1 * gwn; gp2[r] = v2 * gwn; gp3[r] = v3 * gwn; }
    }
    if (GATE) {
#pragma unroll
        for (int r = 0; r < 4; r++) {
#pragma unroll
            for (int s = 1; s < 16; s <<= 1) {
                gp0[r] += __shfl_xor(gp0[r], s, 16);
                gp1[r] += __shfl_xor(gp1[r], s, 16);
                gp2[r] += __shfl_xor(gp2[r], s, 16);
                gp3[r] += __shfl_xor(gp3[r], s, 16);
            }
        }
        __syncthreads();
        if (mm == 0) {
#pragma unroll
            for (int r = 0; r < 4; r++) {
                sgatep[q2 * 4 + r][w] = gp0[r];
                sgatep[16 + q2 * 4 + r][w] = gp1[r];
                sgatep[32 + q2 * 4 + r][w] = gp2[r];
                sgatep[48 + q2 * 4 + r][w] = gp3[r];
            }
        }
        __syncthreads();
        if (tid < NBN) {
            const int n = blockIdx.x * NBN + tid;
            if (n < N_NODES) {
                float s = 0.f;
#pragma unroll
                for (int w8 = 0; w8 < 8; w8++) s += sgatep[tid][w8];
                gate[n] = s + gb[0];
            }
        }
    }
}

// One block (256 threads) per graph: segment softmax + weighted readout + MLP head + sigmoid.
__global__ __launch_bounds__(256) void k_pool(
    const float* __restrict__ h3, const float* __restrict__ gate, const int* __restrict__ n2g,
    const float* __restrict__ fc1w, const float* __restrict__ fc1b,
    const float* __restrict__ fc2w, const float* __restrict__ fc2b,
    const float* __restrict__ fc3w, const float* __restrict__ fc3b,
    float* __restrict__ out, int N) {
    const int g = blockIdx.x;
    const int tid = threadIdx.x;
    __shared__ float sred[256];
    __shared__ float sr[128];
    __shared__ float sz1[100];
    __shared__ float sz2[64];
    __shared__ float sm, ssum;

    const int s = lower_bound_i(n2g, N, g);
    const int e = lower_bound_i(n2g, N, g + 1);

    float m = -3.4e38f;
    for (int n = s + tid; n < e; n += 256) m = fmaxf(m, gate[n]);
    sred[tid] = m;
    __syncthreads();
    for (int off = 128; off > 0; off >>= 1) {
        if (tid < off) sred[tid] = fmaxf(sred[tid], sred[tid + off]);
        __syncthreads();
    }
    if (tid == 0) sm = sred[0];
    __syncthreads();
    const float mm = sm;

    float sum = 0.f;
    for (int n = s + tid; n < e; n += 256) sum += expf(gate[n] - mm);
    sred[tid] = sum;
    __syncthreads();
    for (int off = 128; off > 0; off >>= 1) {
        if (tid < off) sred[tid] += sred[tid + off];
        __syncthreads();
    }
    if (tid == 0) ssum = sred[0];
    __syncthreads();
    const float inv = (e > s) ? 1.0f / ssum : 0.f;

    const int col = tid & 127;
    const int half = tid >> 7;
    float acc = 0.f;
    int n = s + half;
    for (; n + 6 < e; n += 8) {
        const float w0 = expf(gate[n] - mm);
        const float w1 = expf(gate[n + 2] - mm);
        const float w2 = expf(gate[n + 4] - mm);
        const float w3 = expf(gate[n + 6] - mm);
        const float a0 = h3[(size_t)n * DIM + col];
        const float a1 = h3[(size_t)(n + 2) * DIM + col];
        const float a2 = h3[(size_t)(n + 4) * DIM + col];
        const float a3 = h3[(size_t)(n + 6) * DIM + col];
        acc = fmaf(w0, a0, acc);
        acc = fmaf(w1, a1, acc);
        acc = fmaf(w2, a2, acc);
        acc = fmaf(w3, a3, acc);
    }
    for (; n < e; n += 2) {
        const float wgt = expf(gate[n] - mm);
        acc = fmaf(wgt, h3[(size_t)n * DIM + col], acc);
    }
    sred[tid] = acc;
    __syncthreads();
    if (tid < 128) sr[tid] = (sred[tid] + sred[tid + 128]) * inv;
    __syncthreads();

    if (tid < 100) {
        float t = fc1b[tid];
        for (int i = 0; i < 128; i++) t = fmaf(sr[i], fc1w[i * 100 + tid], t);
        sz1[tid] = fmaxf(t, 0.f);
    }
    __syncthreads();
    if (tid < 64) {
        float t = fc2b[tid];
        for (int i = 0; i < 100; i++) t = fmaf(sz1[i], fc2w[i * 64 + tid], t);
        sz2[tid] = fmaxf(t, 0.f);
    }
    __syncthreads();
    if (tid < 64) {
        float p = sz2[tid] * fc3w[tid];
#pragma unroll
        for (int off = 32; off > 0; off >>= 1) p += __shfl_down(p, off, 64);
        if (tid == 0) {
            const float z = p + fc3b[0];
            out[g] = 1.0f / (1.0f + expf(-z));
        }
    }
}

extern "C" void kernel_launch(void* const* d_in, const int* in_sizes, int n_in,
                              void* d_out, int out_size, void* d_ws, size_t ws_size,
                              hipStream_t stream) {
    (void)in_sizes; (void)n_in; (void)out_size; (void)ws_size;
    const float* features = (const float*)d_in[0];
    const int*   src      = (const int*)d_in[1];
    const int*   dst      = (const int*)d_in[2];
    const int*   etype    = (const int*)d_in[3];
    const int*   n2g      = (const int*)d_in[4];
    const float* bases1   = (const float*)d_in[5];
    const float* comp1    = (const float*)d_in[6];
    const float* bias1    = (const float*)d_in[7];
    const float* bases2   = (const float*)d_in[8];
    const float* comp2    = (const float*)d_in[9];
    const float* bias2    = (const float*)d_in[10];
    const float* bases3   = (const float*)d_in[11];
    const float* comp3    = (const float*)d_in[12];
    const float* bias3    = (const float*)d_in[13];
    const float* gate_w   = (const float*)d_in[14];
    const float* gate_b   = (const float*)d_in[15];
    const float* fc1w     = (const float*)d_in[16];
    const float* fc1b     = (const float*)d_in[17];
    const float* fc2w     = (const float*)d_in[18];
    const float* fc2b     = (const float*)d_in[19];
    const float* fc3w     = (const float*)d_in[20];
    const float* fc3b     = (const float*)d_in[21];
    float* out = (float*)d_out;

    char* w = (char*)d_ws;
    auto alloc = [&](size_t bytes) -> char* {
        char* p = w;
        w += (bytes + 255) & ~(size_t)255;
        return p;
    };
    int*    offsets = (int*)alloc((NKEY + 1) * sizeof(int));
    int*    edges   = (int*)alloc((N_EDGES + 16) * sizeof(int));
    float*  hA      = (float*)alloc((size_t)N_NODES * DIM * sizeof(float));
    float*  hB      = (float*)alloc((size_t)N_NODES * DIM * sizeof(float));
    float*  gate    = (float*)alloc(N_NODES * sizeof(float));
    ushort* Whi1    = (ushort*)alloc((size_t)KDIM * DIM * sizeof(ushort));
    ushort* Wlo1    = (ushort*)alloc((size_t)KDIM * DIM * sizeof(ushort));
    ushort* Whi2    = (ushort*)alloc((size_t)KDIM * DIM * sizeof(ushort));
    ushort* Wlo2    = (ushort*)alloc((size_t)KDIM * DIM * sizeof(ushort));
    ushort* Whi3    = (ushort*)alloc((size_t)KDIM * DIM * sizeof(ushort));
    ushort* Wlo3    = (ushort*)alloc((size_t)KDIM * DIM * sizeof(ushort));
    // CSR scratch aliased into hB (hB is first written in layer 2, after CSR build)
    int*    cursor  = (int*)hB;                              // NSEG2*SEG ints = 1.6 MB
    int*    segscan = (int*)((char*)hB + (2u << 20));        // 1.6 MB at +2 MB
    int*    segtot  = (int*)((char*)hB + (4u << 20));
    int*    segbase = (int*)((char*)hB + (4u << 20) + 4096);

    // fused prep: pack W (3 layers) + zero counters
    k_prep<<<1536 + 391, 256, 0, stream>>>(bases1, comp1, Whi1, Wlo1,
                                           bases2, comp2, Whi2, Wlo2,
                                           bases3, comp3, Whi3, Wlo3, cursor);

    // (node,rel)-keyed CSR (rebuilt every call)
    k_count<<<(N_EDGES + 255) / 256, 256, 0, stream>>>(dst, etype, cursor, N_EDGES);
    k_scan_seg<<<NSEG2, 256, 0, stream>>>(cursor, segscan, segtot);
    k_scan_tot<<<1, 512, 0, stream>>>(segtot, segbase);
    k_scan_fin<<<(NKEY + 256) / 256, 256, 0, stream>>>(segscan, segbase, offsets, cursor);
    k_fill<<<(N_EDGES + 255) / 256, 256, 0, stream>>>(src, dst, etype, cursor, edges, N_EDGES);

    // 3 RGCN layers (relation-sorted aggregation + 8-round MFMA GEMM, 64 nodes/block)
    k_layer<true, false><<<NBLK, 512, 0, stream>>>(features, hA, edges, offsets, Whi1, Wlo1, bias1, gate_w, gate_b, gate);
    k_layer<true, false><<<NBLK, 512, 0, stream>>>(hA, hB, edges, offsets, Whi2, Wlo2, bias2, gate_w, gate_b, gate);
    k_layer<false, true><<<NBLK, 512, 0, stream>>>(hB, hA, edges, offsets, Whi3, Wlo3, bias3, gate_w, gate_b, gate);

    // pooling + MLP head (gate computed in layer 3)
    k_pool<<<N_GRAPHS, 256, 0, stream>>>(hA, gate, n2g, fc1w, fc1b, fc2w, fc2b, fc3w, fc3b, out, N_NODES);
}